// Round 4
// baseline (147.338 us; speedup 1.0000x reference)
//
#include <hip/hip_runtime.h>

// VectorQuantizer gather: out[b][d][n] = embedding[indices[b][n]][d]
// B=32, N=4096 (64x64), K=1024, D=256. fp32 out = 128 MiB -> write-BW bound.
//
// v4b = v3 + ONE change: nontemporal output stores (fixed compile: builtin
// needs a native ext_vector type, not HIP_vector_type<float,4>).
//  Discriminator: v1/v2/v3 (wildly different read/write tilings) all land
//  ~59-61 us of non-fill time, vs a 21 us write floor. The only store-path
//  mechanism common to all three is ordinary cached write-allocate stores.
//  v4 flags the output stream nt (bypass L2 dirty-line machinery).
//  Pre-committed read: big drop -> store-path theory confirmed; no change
//  -> kernel already at roofline, residual is fixed harness dispatches
//  (81.7us poison fill + ~40us, likely an output staging copy).

#define VQ_B 32
#define VQ_N 4096
#define VQ_D 256
#define DC 32            // d-chunk per block
#define NT 1024          // n-tile per block
#define NW 256           // n per wave
#define NSUB 32          // n per sub-iteration
#define TSTRIDE 34       // LDS tile row stride in floats (pad vs 32)

typedef float v4f __attribute__((ext_vector_type(4)));

__global__ __launch_bounds__(256, 4) void vq_gather_kernel(
    const int* __restrict__ indices,
    const float* __restrict__ embedding,
    float* __restrict__ out)
{
    __shared__ int   s_idx[NT];
    __shared__ float s_tile[4][NSUB * TSTRIDE];   // per-wave transpose tile

    const int bid = blockIdx.x;
    const int nt  = bid & 3;          // n-tile 0..3
    const int dc  = (bid >> 2) & 7;   // d-chunk 0..7
    const int b   = bid >> 5;         // batch 0..31

    const int t = threadIdx.x;
    const int w = t >> 6;             // wave 0..3
    const int l = t & 63;

    // stage this block's 1024 indices (coalesced, one barrier total)
    #pragma unroll
    for (int k = 0; k < 4; ++k)
        s_idx[t + 256 * k] = indices[b * VQ_N + nt * NT + t + 256 * k];
    __syncthreads();

    // load-phase mapping: 8 lanes cover one 128 B row slice
    const int s  = l & 7;             // float4 slot within row slice
    const int nn = l >> 3;            // row-in-group 0..7
    // store-phase mapping: 8 lanes cover 32 n for one d
    const int ss = l & 7;             // n-quad 0..7
    const int dd = l >> 3;            // d-in-group 0..7

    float* tile = s_tile[w];
    const float* emb_c = embedding + dc * DC;     // column offset into rows
    const int wbase = w * NW;

    float* out_w = out + (b * VQ_D + dc * DC) * VQ_N + nt * NT + wbase;

    float4 v[4], vn[4];

    // prologue: gather sub-tile 0 (4 x float4 per lane = 32 rows x 128 B)
    #pragma unroll
    for (int k = 0; k < 4; ++k) {
        const int row = s_idx[wbase + nn + 8 * k];
        v[k] = ((const float4*)(emb_c + row * VQ_D))[s];
    }

    for (int si = 0; si < 8; ++si) {
        // prefetch next sub-tile's gathers (hide L2 latency under LDS+stores)
        if (si < 7) {
            #pragma unroll
            for (int k = 0; k < 4; ++k) {
                const int row = s_idx[wbase + (si + 1) * NSUB + nn + 8 * k];
                vn[k] = ((const float4*)(emb_c + row * VQ_D))[s];
            }
        }

        // transpose in: tile[n][d]
        #pragma unroll
        for (int k = 0; k < 4; ++k) {
            float* p = &tile[(nn + 8 * k) * TSTRIDE + 4 * s];
            p[0] = v[k].x; p[1] = v[k].y; p[2] = v[k].z; p[3] = v[k].w;
        }

        // transpose out: column reads -> nontemporal float4 stores
        #pragma unroll
        for (int q = 0; q < 4; ++q) {
            const int d = dd + 8 * q;
            v4f o;
            o.x = tile[(4 * ss + 0) * TSTRIDE + d];
            o.y = tile[(4 * ss + 1) * TSTRIDE + d];
            o.z = tile[(4 * ss + 2) * TSTRIDE + d];
            o.w = tile[(4 * ss + 3) * TSTRIDE + d];
            __builtin_nontemporal_store(
                o, (v4f*)(out_w + d * VQ_N + si * NSUB + 4 * ss));
        }

        #pragma unroll
        for (int k = 0; k < 4; ++k) v[k] = vn[k];
    }
}

extern "C" void kernel_launch(void* const* d_in, const int* in_sizes, int n_in,
                              void* d_out, int out_size, void* d_ws, size_t ws_size,
                              hipStream_t stream) {
    const int*   indices   = (const int*)d_in[0];    // (32,1,4096) int32
    const float* embedding = (const float*)d_in[1];  // (1024,256) fp32
    float* out = (float*)d_out;                      // (32,256,64,64) fp32

    vq_gather_kernel<<<dim3(VQ_B * 8 * 4), dim3(256), 0, stream>>>(
        indices, embedding, out);
}